// Round 1
// baseline (39737.170 us; speedup 1.0000x reference)
//
#include <hip/hip_runtime.h>

// RNNT greedy decode, persistent single-kernel implementation.
// B=32, T=100, E=512, H=640, 4H=2560, J=640, V=4096 (BLANK=4096), 200 iterations.
// Grid: 512 blocks x 256 threads, all co-resident (launch_bounds(256,2) => >=2 blocks/CU).
// 3 custom grid barriers per iteration; argmax/logsumexp combined via device-scope
// atomics (u64 packed max + u64 fixed-point sum => fully deterministic).

#define GBLK 512
#define S1BLK 320   // blocks doing LSTM/joint stages (2 j-columns each -> 640 j)

__device__ __forceinline__ unsigned f2ord(float f) {
  unsigned u = __float_as_uint(f);
  return (u & 0x80000000u) ? ~u : (u | 0x80000000u);
}
__device__ __forceinline__ float ord2f(unsigned u) {
  return __uint_as_float((u & 0x80000000u) ? (u & 0x7fffffffu) : ~u);
}
__device__ __forceinline__ unsigned long long shfl_xor_u64(unsigned long long x, int m) {
  int lo = __shfl_xor((int)(unsigned)x, m, 64);
  int hi = __shfl_xor((int)(unsigned)(x >> 32), m, 64);
  return ((unsigned long long)(unsigned)hi << 32) | (unsigned)lo;
}

__device__ __forceinline__ void gsync(unsigned* cnt, unsigned* gen) {
  __syncthreads();
  if (threadIdx.x == 0) {
    __threadfence();  // release this block's writes (agent scope)
    unsigned g = __hip_atomic_load(gen, __ATOMIC_RELAXED, __HIP_MEMORY_SCOPE_AGENT);
    unsigned a = __hip_atomic_fetch_add(cnt, 1u, __ATOMIC_ACQ_REL, __HIP_MEMORY_SCOPE_AGENT);
    if (a == GBLK - 1u) {
      __hip_atomic_store(cnt, 0u, __ATOMIC_RELAXED, __HIP_MEMORY_SCOPE_AGENT);
      __hip_atomic_store(gen, g + 1u, __ATOMIC_RELEASE, __HIP_MEMORY_SCOPE_AGENT);
    } else {
      while (__hip_atomic_load(gen, __ATOMIC_RELAXED, __HIP_MEMORY_SCOPE_AGENT) == g)
        __builtin_amdgcn_s_sleep(1);
    }
    __threadfence();  // acquire side
  }
  __syncthreads();
}

template <int N>
__device__ __forceinline__ float dotN(const float* __restrict__ a,
                                      const float* __restrict__ b, float acc) {
#pragma unroll 8
  for (int k = 0; k < N; k += 4) {
    float4 av = *(const float4*)(a + k);
    float4 bv = *(const float4*)(b + k);
    acc += av.x * bv.x; acc += av.y * bv.y;
    acc += av.z * bv.z; acc += av.w * bv.w;
  }
  return acc;
}

__global__ __launch_bounds__(256, 2) void rnnt_persist(
    const float* __restrict__ enc, const int* __restrict__ lens,
    const float* __restrict__ embed, const float* __restrict__ W_i,
    const float* __restrict__ W_h, const float* __restrict__ b_lstm,
    const float* __restrict__ W_enc, const float* __restrict__ W_pred,
    const float* __restrict__ b_joint, const float* __restrict__ W_out,
    const float* __restrict__ b_out, float* __restrict__ out,
    float* __restrict__ Wcat_t, float* __restrict__ Wpred_t,
    float* __restrict__ Wout_t, float* __restrict__ enc_projB,
    float* __restrict__ h_buf, float* __restrict__ c_buf,
    float* __restrict__ jt,
    unsigned long long* __restrict__ kmax8, unsigned long long* __restrict__ sfx8,
    unsigned* __restrict__ bar) {
  const int blk = blockIdx.x, tid = threadIdx.x;
  const int gtid = blk * 256 + tid;
  unsigned* cnt = bar;
  unsigned* gen = bar + 32;  // separate cacheline

  __shared__ float s_tr[32][33];
  __shared__ float s_zex[4][32][2];
  __shared__ float s_red[4][64];
  __shared__ int s_last[32];
  __shared__ int s_cur[32];

  // ----------------- phase 0: init + weight transposes + enc projection ----
  for (int x = gtid; x < 6400; x += GBLK * 256) out[x] = 4096.0f;  // labels=BLANK
  for (int x = gtid; x < 20480; x += GBLK * 256) { h_buf[x] = 0.f; c_buf[x] = 0.f; }
  for (int x = gtid; x < 512; x += GBLK * 256) { kmax8[x] = 0ull; sfx8[x] = 0ull; }

  {
    const int NT0 = 1600, NT1 = 1600, NT2 = 400, NT3 = 2580;  // 32x32 tiles
    for (int tl = blk; tl < NT0 + NT1 + NT2 + NT3; tl += GBLK) {
      const float* src; float* dst; int C, DS, DO, CT; int tt = tl;
      if (tt < NT0)               { src = W_i;    dst = Wcat_t;  C = 2560; DS = 1280; DO = 0;   CT = 80; }
      else if ((tt -= NT0) < NT1) { src = W_h;    dst = Wcat_t;  C = 2560; DS = 1280; DO = 640; CT = 80; }
      else if ((tt -= NT1) < NT2) { src = W_pred; dst = Wpred_t; C = 640;  DS = 640;  DO = 0;   CT = 20; }
      else { tt -= NT2;             src = W_out;  dst = Wout_t;  C = 4097; DS = 640;  DO = 0;   CT = 129; }
      int rt = tt / CT, ct = tt % CT;
      int r0 = rt * 32, c0 = ct * 32;
      __syncthreads();
#pragma unroll
      for (int p = 0; p < 4; ++p) {
        int rr = (tid >> 5) + 8 * p, cc = tid & 31;
        float v = 0.f;
        if (c0 + cc < C) v = src[(r0 + rr) * C + c0 + cc];
        s_tr[rr][cc] = v;
      }
      __syncthreads();
#pragma unroll
      for (int p = 0; p < 4; ++p) {
        int cc2 = (tid >> 5) + 8 * p, rr2 = tid & 31;
        if (c0 + cc2 < C) dst[(c0 + cc2) * DS + DO + r0 + rr2] = s_tr[rr2][cc2];
      }
    }
  }

  // enc_projB[b][t][j] = sum_e enc[b][e][t] * W_enc[e][j] + b_joint[j]
  for (int idx = gtid; idx < 2048000; idx += GBLK * 256) {
    int b = idx / 64000, r = idx % 64000;
    int tt = r / 640, j = r % 640;
    const float* ep = enc + b * 51200;
    float acc = b_joint[j];
#pragma unroll 4
    for (int e = 0; e < 512; ++e) acc += ep[e * 100 + tt] * W_enc[e * 640 + j];
    enc_projB[idx] = acc;
  }

  gsync(cnt, gen);

  // persistent per-lane decoder state (lanes 0..31 of stage-1 blocks track batch=lane)
  int last_r = 4096, cur_r = 0, cnt_r = 0;
  bool blank_r = false;
  float score_r = 0.f;

  for (int i = 0; i <= 200; ++i) {
    // ---- prologue: redundant per-block decision of iteration i-1 ----
    if (blk < S1BLK) {
      if (tid < 32) {
        int b = tid;
        if (i > 0) {
          int pi = (i - 1) & 1;
          const unsigned long long* kk = kmax8 + (pi * 32 + b) * 8;
          const unsigned long long* ssp = sfx8 + (pi * 32 + b) * 8;
          unsigned long long key = 0ull, sum = 0ull;
#pragma unroll
          for (int c = 0; c < 8; ++c) {
            unsigned long long kv = kk[c];
            if (kv > key) key = kv;
            sum += ssp[c];
          }
          int kArg = 4096 - (int)(key & 0xffffffffu);
          float bl = ord2f((unsigned)(key >> 32));
          float lse = logf((float)sum * 0x1p-32f);
          float vsc = bl - lse;
          int im1 = i - 1, tp = im1 >> 1, sp = im1 & 1;
          bool blank_in = (sp == 0) ? (tp >= lens[b]) : blank_r;
          bool nb = blank_in || (kArg == 4096);
          blank_r = nb;
          if (!nb) { last_r = kArg; cur_r ^= 1; }
          if (blk == b) {  // publisher block for this batch
            if (!nb) { out[b * 200 + cnt_r] = (float)kArg; cnt_r++; score_r += vsc; }
            if (i == 200) { out[6400 + b] = (float)cnt_r; out[6432 + b] = score_r; }
          }
        }
        s_last[b] = last_r;
        s_cur[b] = cur_r;
      }
    } else if (blk >= 480) {
      // reset the atomic slot stage-4 will write this iteration
      if (i < 200 && tid < 16) {
        int b = blk - 480, p2 = i & 1;
        if (tid < 8) kmax8[(p2 * 32 + b) * 8 + tid] = 0ull;
        else         sfx8[(p2 * 32 + b) * 8 + (tid - 8)] = 0ull;
      }
    }
    __syncthreads();
    if (i == 200) return;
    const int t = i >> 1;

    // ---- stage 1: LSTM z = [x;h] @ [W_i;W_h] + b, then gates ----
    if (blk < S1BLK) {
      int g = tid >> 6, lane6 = tid & 63;
      int b = lane6 >> 1, j_l = lane6 & 1;
      int j = blk * 2 + j_l, col = g * 640 + j;
      float acc = b_lstm[col];
      if (i > 0) {  // i==0: SOS (x=0) and h=0 -> z = bias
        const float* wt = Wcat_t + col * 1280;
        const float* xrow = embed + s_last[b] * 640;
        const float* hrow = h_buf + (s_cur[b] * 32 + b) * 640;
        acc = dotN<640>(wt, xrow, acc);
        acc = dotN<640>(wt + 640, hrow, acc);
      }
      s_zex[g][b][j_l] = acc;
    }
    __syncthreads();
    if (blk < S1BLK && tid < 64) {
      int b = tid >> 1, j_l = tid & 1, j = blk * 2 + j_l;
      float zi = s_zex[0][b][j_l], zf = s_zex[1][b][j_l];
      float zg = s_zex[2][b][j_l], zo = s_zex[3][b][j_l];
      int cu = s_cur[b], nc2 = cu ^ 1;
      float cold = c_buf[(cu * 32 + b) * 640 + j];
      float ig = 1.f / (1.f + expf(-zi));
      float fg = 1.f / (1.f + expf(-zf));
      float og = 1.f / (1.f + expf(-zo));
      float cn = fg * cold + ig * tanhf(zg);
      float hn = og * tanhf(cn);
      h_buf[(nc2 * 32 + b) * 640 + j] = hn;
      c_buf[(nc2 * 32 + b) * 640 + j] = cn;
    }
    gsync(cnt, gen);

    // ---- stage 3: jt = relu(enc_projB[:,t] + h1 @ W_pred) ----
    if (blk < S1BLK) {
      int w = tid >> 6, lane6 = tid & 63;
      int b = lane6 >> 1, j_l = lane6 & 1;
      int j = blk * 2 + j_l;
      const float* h1row = h_buf + ((s_cur[b] ^ 1) * 32 + b) * 640 + w * 160;
      const float* wp = Wpred_t + j * 640 + w * 160;
      s_red[w][lane6] = dotN<160>(wp, h1row, 0.f);
    }
    __syncthreads();
    if (blk < S1BLK && tid < 64) {
      int b = tid >> 1, j_l = tid & 1, j = blk * 2 + j_l;
      float sm = s_red[0][tid] + s_red[1][tid] + s_red[2][tid] + s_red[3][tid];
      float val = enc_projB[(b * 100 + t) * 640 + j] + sm;
      jt[b * 640 + j] = fmaxf(val, 0.f);
    }
    gsync(cnt, gen);

    // ---- stage 4: logits = jt @ W_out + b_out; argmax + fixed-point sumexp ----
    {
      int b = tid >> 3, v_l = tid & 7;
      int v = blk * 8 + v_l;  // 0..4095
      const float* wo = Wout_t + v * 640;
      const float* jr = jt + b * 640;
      float acc = dotN<640>(wo, jr, b_out[v]);
      unsigned long long key =
          ((unsigned long long)f2ord(acc) << 32) | (unsigned)(4096 - v);
      unsigned long long isum =
          (unsigned long long)(expf(acc) * 4294967296.0f + 0.5f);
#pragma unroll
      for (int d = 1; d < 8; d <<= 1) {
        unsigned long long ok = shfl_xor_u64(key, d);
        if (ok > key) key = ok;
        isum += shfl_xor_u64(isum, d);
      }
      int p = i & 1;
      if (v_l == 0) {
        atomicMax(&kmax8[(p * 32 + b) * 8 + (blk & 7)], key);
        atomicAdd(&sfx8[(p * 32 + b) * 8 + (blk & 7)], isum);
      }
      if (blk == GBLK - 1 && tid < 32) {  // the BLANK column v=4096
        int b2 = tid;
        float a2 = dotN<640>(Wout_t + 4096 * 640, jt + b2 * 640, b_out[4096]);
        unsigned long long key2 = ((unsigned long long)f2ord(a2) << 32);
        unsigned long long is2 =
            (unsigned long long)(expf(a2) * 4294967296.0f + 0.5f);
        atomicMax(&kmax8[(p * 32 + b2) * 8 + 7], key2);
        atomicAdd(&sfx8[(p * 32 + b2) * 8 + 7], is2);
      }
    }
    gsync(cnt, gen);
  }
}

extern "C" void kernel_launch(void* const* d_in, const int* in_sizes, int n_in,
                              void* d_out, int out_size, void* d_ws, size_t ws_size,
                              hipStream_t stream) {
  (void)in_sizes; (void)n_in; (void)out_size; (void)ws_size;
  const float* enc    = (const float*)d_in[0];
  const int*   lens   = (const int*)d_in[1];
  const float* embed  = (const float*)d_in[2];
  const float* W_i    = (const float*)d_in[3];
  const float* W_h    = (const float*)d_in[4];
  const float* b_lstm = (const float*)d_in[5];
  const float* W_enc  = (const float*)d_in[6];
  const float* W_pred = (const float*)d_in[7];
  const float* b_joint= (const float*)d_in[8];
  const float* W_out  = (const float*)d_in[9];
  const float* b_out  = (const float*)d_in[10];
  float* out = (float*)d_out;

  char* ws = (char*)d_ws;
  size_t off = 0;
  auto carve = [&](size_t bytes) -> void* {
    void* p = ws + off;
    off += (bytes + 255) & ~(size_t)255;
    return p;
  };
  unsigned* bar              = (unsigned*)carve(256);
  unsigned long long* kmax8  = (unsigned long long*)carve(2 * 32 * 8 * 8);
  unsigned long long* sfx8   = (unsigned long long*)carve(2 * 32 * 8 * 8);
  float* jt       = (float*)carve((size_t)32 * 640 * 4);
  float* h_buf    = (float*)carve((size_t)2 * 32 * 640 * 4);
  float* c_buf    = (float*)carve((size_t)2 * 32 * 640 * 4);
  float* Wpred_t  = (float*)carve((size_t)640 * 640 * 4);
  float* Wcat_t   = (float*)carve((size_t)2560 * 1280 * 4);
  float* Wout_t   = (float*)carve((size_t)4097 * 640 * 4);
  float* enc_projB= (float*)carve((size_t)32 * 100 * 640 * 4);

  hipMemsetAsync(bar, 0, 256, stream);  // barrier counter + generation
  rnnt_persist<<<GBLK, 256, 0, stream>>>(
      enc, lens, embed, W_i, W_h, b_lstm, W_enc, W_pred, b_joint, W_out, b_out,
      out, Wcat_t, Wpred_t, Wout_t, enc_projB, h_buf, c_buf, jt, kmax8, sfx8, bar);
}

// Round 2
// 38918.295 us; speedup vs baseline: 1.0210x; 1.0210x over previous
//
#include <hip/hip_runtime.h>

// RNNT greedy decode. B=32, T=100, E=512, H=640, 4H=2560, J=640, V=4096 (BLANK).
// Two kernels: rnnt_prep (transposes + enc projection + state init, 2048 blocks),
// rnnt_decode (persistent, 512 blocks x 256 threads, 200 iterations).
// Grid barrier v2: per-block arrival flags (64B padded, release stores, no RMW),
// master block polls the flag array, fan-out release over 64 padded "go" lines.

#define NB 512
#define S1BLK 320   // blocks doing LSTM/joint stages (2 j-columns each -> 640 j)

__device__ __forceinline__ unsigned f2ord(float f) {
  unsigned u = __float_as_uint(f);
  return (u & 0x80000000u) ? ~u : (u | 0x80000000u);
}
__device__ __forceinline__ float ord2f(unsigned u) {
  return __uint_as_float((u & 0x80000000u) ? (u & 0x7fffffffu) : ~u);
}
__device__ __forceinline__ unsigned long long shfl_xor_u64(unsigned long long x, int m) {
  int lo = __shfl_xor((int)(unsigned)x, m, 64);
  int hi = __shfl_xor((int)(unsigned)(x >> 32), m, 64);
  return ((unsigned long long)(unsigned)hi << 32) | (unsigned)lo;
}

// ---- grid barrier: flag array + fan-out release ----
__device__ __forceinline__ void gsync(unsigned* __restrict__ arrive,
                                      unsigned* __restrict__ go, unsigned it) {
  const int blk = blockIdx.x, tid = threadIdx.x;
  __syncthreads();
  if (tid == 0) {
    __threadfence();  // make this block's writes visible device-wide
    __hip_atomic_store(&arrive[blk * 16], it, __ATOMIC_RELEASE, __HIP_MEMORY_SCOPE_AGENT);
  }
  if (blk == 0) {
    if (tid < 64) {
      const int base = tid * 8;  // 64 lanes x 8 flags = 512
      for (;;) {
        bool ok = true;
#pragma unroll
        for (int k = 0; k < 8; ++k) {
          unsigned v = __hip_atomic_load(&arrive[(base + k) * 16], __ATOMIC_RELAXED,
                                         __HIP_MEMORY_SCOPE_AGENT);
          ok &= (v >= it);
        }
        if (__all(ok)) break;
        __builtin_amdgcn_s_sleep(2);
      }
    }
    __syncthreads();
    if (tid < 64) {
      __threadfence();
      __hip_atomic_store(&go[tid * 16], it, __ATOMIC_RELEASE, __HIP_MEMORY_SCOPE_AGENT);
    }
    __syncthreads();
  } else {
    if (tid == 0) {
      while (__hip_atomic_load(&go[(blk & 63) * 16], __ATOMIC_RELAXED,
                               __HIP_MEMORY_SCOPE_AGENT) < it)
        __builtin_amdgcn_s_sleep(2);
      __threadfence();  // acquire: invalidate stale cached data
    }
    __syncthreads();
  }
}

template <int N>
__device__ __forceinline__ float dotN(const float* __restrict__ a,
                                      const float* __restrict__ b, float acc) {
#pragma unroll 8
  for (int k = 0; k < N; k += 4) {
    float4 av = *(const float4*)(a + k);
    float4 bv = *(const float4*)(b + k);
    acc += av.x * bv.x; acc += av.y * bv.y;
    acc += av.z * bv.z; acc += av.w * bv.w;
  }
  return acc;
}

// ----------------- prep: init + weight transposes + enc projection -----------
__global__ __launch_bounds__(256) void rnnt_prep(
    const float* __restrict__ enc, const float* __restrict__ W_i,
    const float* __restrict__ W_h, const float* __restrict__ W_pred,
    const float* __restrict__ W_out, const float* __restrict__ W_enc,
    const float* __restrict__ b_joint,
    float* __restrict__ out, float* __restrict__ Wcat_t,
    float* __restrict__ Wpred_t, float* __restrict__ Wout_t,
    float* __restrict__ enc_projB, float* __restrict__ h_buf,
    float* __restrict__ c_buf, unsigned long long* __restrict__ kmax8,
    unsigned long long* __restrict__ sfx8, unsigned* __restrict__ arrive,
    unsigned* __restrict__ go) {
  const int blk = blockIdx.x, tid = threadIdx.x;
  const int gtid = blk * 256 + tid;
  const int GT = gridDim.x * 256;
  __shared__ float s_tr[32][33];

  for (int x = gtid; x < 6464; x += GT) out[x] = (x < 6400) ? 4096.0f : 0.0f;
  for (int x = gtid; x < 40960; x += GT) { h_buf[x] = 0.f; c_buf[x] = 0.f; }
  for (int x = gtid; x < 512; x += GT) { kmax8[x] = 0ull; sfx8[x] = 0ull; }
  for (int x = gtid; x < NB * 16; x += GT) arrive[x] = 0u;
  for (int x = gtid; x < 64 * 16; x += GT) go[x] = 0u;

  {
    const int NT0 = 1600, NT1 = 1600, NT2 = 400, NT3 = 2580;  // 32x32 tiles
    for (int tl = blk; tl < NT0 + NT1 + NT2 + NT3; tl += gridDim.x) {
      const float* src; float* dst; int C, DS, DO, CT; int tt = tl;
      if (tt < NT0)               { src = W_i;    dst = Wcat_t;  C = 2560; DS = 1280; DO = 0;   CT = 80; }
      else if ((tt -= NT0) < NT1) { src = W_h;    dst = Wcat_t;  C = 2560; DS = 1280; DO = 640; CT = 80; }
      else if ((tt -= NT1) < NT2) { src = W_pred; dst = Wpred_t; C = 640;  DS = 640;  DO = 0;   CT = 20; }
      else { tt -= NT2;             src = W_out;  dst = Wout_t;  C = 4097; DS = 640;  DO = 0;   CT = 129; }
      int rt = tt / CT, ct = tt % CT;
      int r0 = rt * 32, c0 = ct * 32;
      __syncthreads();
#pragma unroll
      for (int p = 0; p < 4; ++p) {
        int rr = (tid >> 5) + 8 * p, cc = tid & 31;
        float v = 0.f;
        if (c0 + cc < C) v = src[(r0 + rr) * C + c0 + cc];
        s_tr[rr][cc] = v;
      }
      __syncthreads();
#pragma unroll
      for (int p = 0; p < 4; ++p) {
        int cc2 = (tid >> 5) + 8 * p, rr2 = tid & 31;
        if (c0 + cc2 < C) dst[(c0 + cc2) * DS + DO + r0 + rr2] = s_tr[rr2][cc2];
      }
    }
  }

  // enc_projB[b][t][j] = sum_e enc[b][e][t] * W_enc[e][j] + b_joint[j]
  for (int idx = gtid; idx < 2048000; idx += GT) {
    int b = idx / 64000, r = idx % 64000;
    int tt = r / 640, j = r % 640;
    const float* ep = enc + b * 51200;
    float acc = b_joint[j];
#pragma unroll 4
    for (int e = 0; e < 512; ++e) acc += ep[e * 100 + tt] * W_enc[e * 640 + j];
    enc_projB[idx] = acc;
  }
}

// ----------------- decode: persistent loop ----------------------------------
__global__ __launch_bounds__(256, 2) void rnnt_decode(
    const int* __restrict__ lens, const float* __restrict__ embed,
    const float* __restrict__ b_lstm, const float* __restrict__ b_out,
    float* __restrict__ out,
    const float* __restrict__ Wcat_t, const float* __restrict__ Wpred_t,
    const float* __restrict__ Wout_t, const float* __restrict__ enc_projB,
    float* __restrict__ h_buf, float* __restrict__ c_buf,
    float* __restrict__ jt,
    unsigned long long* __restrict__ kmax8, unsigned long long* __restrict__ sfx8,
    unsigned* __restrict__ arrive, unsigned* __restrict__ go) {
  const int blk = blockIdx.x, tid = threadIdx.x;

  __shared__ float s_zex[4][32][2];
  __shared__ float s_red[4][64];
  __shared__ int s_last[32];
  __shared__ int s_cur[32];

  // persistent per-lane decoder state (lanes 0..31 of stage-1 blocks track batch=lane)
  int last_r = 4096, cur_r = 0, cnt_r = 0;
  bool blank_r = false;
  float score_r = 0.f;
  unsigned it = 0;

  for (int i = 0; i <= 200; ++i) {
    // ---- prologue: redundant per-block decision of iteration i-1 ----
    if (blk < S1BLK) {
      if (tid < 32) {
        int b = tid;
        if (i > 0) {
          int pi = (i - 1) & 1;
          const unsigned long long* kk = kmax8 + (pi * 32 + b) * 8;
          const unsigned long long* ssp = sfx8 + (pi * 32 + b) * 8;
          unsigned long long key = 0ull, sum = 0ull;
#pragma unroll
          for (int c = 0; c < 8; ++c) {
            unsigned long long kv = kk[c];
            if (kv > key) key = kv;
            sum += ssp[c];
          }
          int kArg = 4096 - (int)(key & 0xffffffffu);
          float bl = ord2f((unsigned)(key >> 32));
          float lse = logf((float)sum * 0x1p-32f);
          float vsc = bl - lse;
          int im1 = i - 1, tp = im1 >> 1, sp = im1 & 1;
          bool blank_in = (sp == 0) ? (tp >= lens[b]) : blank_r;
          bool nb = blank_in || (kArg == 4096);
          blank_r = nb;
          if (!nb) { last_r = kArg; cur_r ^= 1; }
          if (blk == b) {  // publisher block for this batch
            if (!nb) { out[b * 200 + cnt_r] = (float)kArg; cnt_r++; score_r += vsc; }
            if (i == 200) { out[6400 + b] = (float)cnt_r; out[6432 + b] = score_r; }
          }
        }
        s_last[b] = last_r;
        s_cur[b] = cur_r;
      }
    } else if (blk >= 480) {
      // reset the atomic slot stage-4 will write this iteration
      if (i < 200 && tid < 16) {
        int b = blk - 480, p2 = i & 1;
        if (tid < 8) kmax8[(p2 * 32 + b) * 8 + tid] = 0ull;
        else         sfx8[(p2 * 32 + b) * 8 + (tid - 8)] = 0ull;
      }
    }
    __syncthreads();
    if (i == 200) return;
    const int t = i >> 1;

    // ---- stage 1: LSTM z = [x;h] @ [W_i;W_h] + b, then gates ----
    if (blk < S1BLK) {
      int g = tid >> 6, lane6 = tid & 63;
      int b = lane6 >> 1, j_l = lane6 & 1;
      int j = blk * 2 + j_l, col = g * 640 + j;
      float acc = b_lstm[col];
      if (i > 0) {  // i==0: SOS (x=0) and h=0 -> z = bias
        const float* wt = Wcat_t + col * 1280;
        const float* xrow = embed + s_last[b] * 640;
        const float* hrow = h_buf + (s_cur[b] * 32 + b) * 640;
        acc = dotN<640>(wt, xrow, acc);
        acc = dotN<640>(wt + 640, hrow, acc);
      }
      s_zex[g][b][j_l] = acc;
    }
    __syncthreads();
    if (blk < S1BLK && tid < 64) {
      int b = tid >> 1, j_l = tid & 1, j = blk * 2 + j_l;
      float zi = s_zex[0][b][j_l], zf = s_zex[1][b][j_l];
      float zg = s_zex[2][b][j_l], zo = s_zex[3][b][j_l];
      int cu = s_cur[b], nc2 = cu ^ 1;
      float cold = c_buf[(cu * 32 + b) * 640 + j];
      float ig = 1.f / (1.f + expf(-zi));
      float fg = 1.f / (1.f + expf(-zf));
      float og = 1.f / (1.f + expf(-zo));
      float cn = fg * cold + ig * tanhf(zg);
      float hn = og * tanhf(cn);
      h_buf[(nc2 * 32 + b) * 640 + j] = hn;
      c_buf[(nc2 * 32 + b) * 640 + j] = cn;
    }
    gsync(arrive, go, ++it);

    // ---- stage 3: jt = relu(enc_projB[:,t] + h1 @ W_pred) ----
    if (blk < S1BLK) {
      int w = tid >> 6, lane6 = tid & 63;
      int b = lane6 >> 1, j_l = lane6 & 1;
      int j = blk * 2 + j_l;
      const float* h1row = h_buf + ((s_cur[b] ^ 1) * 32 + b) * 640 + w * 160;
      const float* wp = Wpred_t + j * 640 + w * 160;
      s_red[w][lane6] = dotN<160>(wp, h1row, 0.f);
    }
    __syncthreads();
    if (blk < S1BLK && tid < 64) {
      int b = tid >> 1, j_l = tid & 1, j = blk * 2 + j_l;
      float sm = s_red[0][tid] + s_red[1][tid] + s_red[2][tid] + s_red[3][tid];
      float val = enc_projB[(b * 100 + t) * 640 + j] + sm;
      jt[b * 640 + j] = fmaxf(val, 0.f);
    }
    gsync(arrive, go, ++it);

    // ---- stage 4: logits = jt @ W_out + b_out; argmax + fixed-point sumexp ----
    {
      int b = tid >> 3, v_l = tid & 7;
      int v = blk * 8 + v_l;  // 0..4095
      const float* wo = Wout_t + v * 640;
      const float* jr = jt + b * 640;
      float acc = dotN<640>(wo, jr, b_out[v]);
      unsigned long long key =
          ((unsigned long long)f2ord(acc) << 32) | (unsigned)(4096 - v);
      unsigned long long isum =
          (unsigned long long)(expf(acc) * 4294967296.0f + 0.5f);
#pragma unroll
      for (int d = 1; d < 8; d <<= 1) {
        unsigned long long ok = shfl_xor_u64(key, d);
        if (ok > key) key = ok;
        isum += shfl_xor_u64(isum, d);
      }
      int p = i & 1;
      if (v_l == 0) {
        atomicMax(&kmax8[(p * 32 + b) * 8 + (blk & 7)], key);
        atomicAdd(&sfx8[(p * 32 + b) * 8 + (blk & 7)], isum);
      }
      if (blk == NB - 1 && tid < 32) {  // the BLANK column v=4096
        int b2 = tid;
        float a2 = dotN<640>(Wout_t + 4096 * 640, jt + b2 * 640, b_out[4096]);
        unsigned long long key2 = ((unsigned long long)f2ord(a2) << 32);
        unsigned long long is2 =
            (unsigned long long)(expf(a2) * 4294967296.0f + 0.5f);
        atomicMax(&kmax8[(p * 32 + b2) * 8 + 7], key2);
        atomicAdd(&sfx8[(p * 32 + b2) * 8 + 7], is2);
      }
    }
    gsync(arrive, go, ++it);
  }
}

extern "C" void kernel_launch(void* const* d_in, const int* in_sizes, int n_in,
                              void* d_out, int out_size, void* d_ws, size_t ws_size,
                              hipStream_t stream) {
  (void)in_sizes; (void)n_in; (void)out_size; (void)ws_size;
  const float* enc    = (const float*)d_in[0];
  const int*   lens   = (const int*)d_in[1];
  const float* embed  = (const float*)d_in[2];
  const float* W_i    = (const float*)d_in[3];
  const float* W_h    = (const float*)d_in[4];
  const float* b_lstm = (const float*)d_in[5];
  const float* W_enc  = (const float*)d_in[6];
  const float* W_pred = (const float*)d_in[7];
  const float* b_joint= (const float*)d_in[8];
  const float* W_out  = (const float*)d_in[9];
  const float* b_out  = (const float*)d_in[10];
  float* out = (float*)d_out;

  char* ws = (char*)d_ws;
  size_t off = 0;
  auto carve = [&](size_t bytes) -> void* {
    void* p = ws + off;
    off += (bytes + 255) & ~(size_t)255;
    return p;
  };
  unsigned* arrive           = (unsigned*)carve(NB * 16 * 4);
  unsigned* go               = (unsigned*)carve(64 * 16 * 4);
  unsigned long long* kmax8  = (unsigned long long*)carve(2 * 32 * 8 * 8);
  unsigned long long* sfx8   = (unsigned long long*)carve(2 * 32 * 8 * 8);
  float* jt       = (float*)carve((size_t)32 * 640 * 4);
  float* h_buf    = (float*)carve((size_t)2 * 32 * 640 * 4);
  float* c_buf    = (float*)carve((size_t)2 * 32 * 640 * 4);
  float* Wpred_t  = (float*)carve((size_t)640 * 640 * 4);
  float* Wcat_t   = (float*)carve((size_t)2560 * 1280 * 4);
  float* Wout_t   = (float*)carve((size_t)4097 * 640 * 4);
  float* enc_projB= (float*)carve((size_t)32 * 100 * 640 * 4);

  rnnt_prep<<<2048, 256, 0, stream>>>(
      enc, W_i, W_h, W_pred, W_out, W_enc, b_joint,
      out, Wcat_t, Wpred_t, Wout_t, enc_projB, h_buf, c_buf, kmax8, sfx8,
      arrive, go);
  rnnt_decode<<<NB, 256, 0, stream>>>(
      lens, embed, b_lstm, b_out, out,
      Wcat_t, Wpred_t, Wout_t, enc_projB, h_buf, c_buf, jt, kmax8, sfx8,
      arrive, go);
}